// Round 15
// baseline (182.493 us; speedup 1.0000x reference)
//
#include <hip/hip_runtime.h>

#define N 4096

__device__ __forceinline__ float bf2f(unsigned short h)
{
    unsigned int u = ((unsigned int)h) << 16;
    return __uint_as_float(u);
}
__device__ __forceinline__ unsigned short f2bf(float f)
{
    unsigned int x = __float_as_uint(f);
    unsigned int r = (x + 0x7FFFu + ((x >> 16) & 1u)) >> 16;  // round-nearest-even
    return (unsigned short)r;
}

// floor(i/2) valid for i >= -1024
__device__ __forceinline__ int cr(int i) { return ((i + 1024) >> 1) - 512; }

__device__ __forceinline__ void load_A(const float* __restrict__ Ag,
                                       float Ac[3][3], float& inv)
{
#pragma unroll
    for (int i = 0; i < 9; ++i) Ac[i / 3][i % 3] = Ag[i];
    inv = 1.0f / Ac[1][1];
    Ac[1][1] = 0.f;
}

__device__ __forceinline__ void make_w44(const float Ac[3][3], float wt[4][4])
{
#pragma unroll
    for (int a = 0; a < 4; ++a)
#pragma unroll
        for (int b = 0; b < 4; ++b) wt[a][b] = 0.f;
#pragma unroll
    for (int r = 0; r < 2; ++r)
#pragma unroll
        for (int c = 0; c < 2; ++c)
#pragma unroll
            for (int i = 0; i < 3; ++i)
#pragma unroll
                for (int j = 0; j < 3; ++j) wt[r + i][c + j] += Ac[i][j];
}

// Branch-free u_bc row segment (f32 or bf16 storage; math in f32).
template <typename TI>
__device__ __forceinline__ void load_row6T(const TI* __restrict__ u,
                                           int gy, int xm, int colL, int colR,
                                           bool cornL, bool cornR, bool yedge,
                                           float v[6])
{
    int cy = min(max(gy, 0), N - 1);
    const TI* rowp = &u[(size_t)cy * N];
    float L, R;
    if constexpr (sizeof(TI) == 4) {
        float4 m = *(const float4*)&rowp[xm];
        v[1] = m.x; v[2] = m.y; v[3] = m.z; v[4] = m.w;
        L = rowp[colL];
        R = rowp[colR];
    } else {
        ushort4 m = *(const ushort4*)&rowp[xm];
        v[1] = bf2f(m.x); v[2] = bf2f(m.y); v[3] = bf2f(m.z); v[4] = bf2f(m.w);
        L = bf2f(rowp[colL]);
        R = bf2f(rowp[colR]);
    }
    if (yedge) {
        bool oob = (gy < 0) | (gy >= N);
        if (oob & cornL) L = 0.f;
        if (oob & cornR) R = 0.f;
    }
    v[0] = L; v[5] = R;
}

// XCD-aware bijective swizzle for 2048-block 1D grids (2048 % 8 == 0).
__device__ __forceinline__ void swz2048(int bid, int& bx, int& by)
{
    int reg = (bid & 7) * 256 + (bid >> 3);
    bx = reg & 15;
    by = reg >> 4;
}

// ---- fused smooth(bc(u)) + restrict + restrict -> r2(bf16, 1024^2) + r3(f32, 512^2) ----
template <typename TI>
__global__ __launch_bounds__(256) void smooth_restrict2_kernel(
    const TI* __restrict__ u, const float* __restrict__ Ag,
    unsigned short* __restrict__ r2, float* __restrict__ r3)
{
    int t = threadIdx.x, lane = t & 63, w = t >> 6;
    int bx, by;
    swz2048(blockIdx.x, bx, by);
    int x0 = 256 * bx;
    int Y0 = 16 * by + 4 * w;
    int gy0 = 2 * Y0 - 1;
    bool yedge = (gy0 < 0) | (gy0 + 9 >= N);
    float Ac[3][3], inv;
    load_A(Ag, Ac, inv);
    float wt[4][4];
    make_w44(Ac, wt);

    int xm = x0 + 4 * lane;
    int colL = max(xm - 1, 0), colR = min(xm + 4, N - 1);
    bool cornL = (xm - 1 < 0), cornR = (xm + 4 >= N);
    float v[10][6];
#pragma unroll
    for (int rr = 0; rr < 10; ++rr)
        load_row6T<TI>(u, gy0 + rr, xm, colL, colR, cornL, cornR, yedge, v[rr]);

    float o0[4], o1[4];
#pragma unroll
    for (int q = 0; q < 4; ++q) {
        float a0 = 0.f, a1 = 0.f;
#pragma unroll
        for (int a = 0; a < 4; ++a) {
            const float* vv = v[2 * q + a];
#pragma unroll
            for (int b = 0; b < 4; ++b) {
                a0 += wt[a][b] * vv[b];
                a1 += wt[a][b] * vv[b + 2];
            }
        }
        o0[q] = 0.25f * a0;
        o1[q] = 0.25f * a1;
    }
    int Y2 = Y0 >> 1, X2 = 64 * bx + lane;   // Y2 even
    float val0 = 0.25f * (o0[0] + o1[0] + o0[1] + o1[1]);
    float val1 = 0.25f * (o0[2] + o1[2] + o0[3] + o1[3]);
    r2[(size_t)Y2 * 1024 + X2] = f2bf(val0);
    r2[(size_t)(Y2 + 1) * 1024 + X2] = f2bf(val1);
    float s0 = val0 + val1;
    float s1 = __shfl_xor(s0, 1);
    if (!(lane & 1))
        r3[(size_t)(Y2 >> 1) * 512 + (X2 >> 1)] = 0.25f * (s0 + s1);
}

// ---- fused: r3 region pyramid (r4..r7) + full e-chain + e2048(regs) + u update ----
// TI/TO: float or ushort(bf16) storage for u_in / u_out. r2 stored bf16.
template <typename TI, typename TO, bool WANTMM>
__global__ __launch_bounds__(256) void final_fused_kernel(
    const TI* __restrict__ u, const float* __restrict__ r3,
    const unsigned short* __restrict__ r2, const float* __restrict__ Ag,
    TO* __restrict__ uo, float* __restrict__ partials)
{
    const int n = N;
    int t = threadIdx.x, lane = t & 63, w = t >> 6;
    int bx, by;
    swz2048(blockIdx.x, bx, by);
    int x0 = 256 * bx, y0 = 32 * by;
    __shared__ float sr3[48][66];   // r3 region, zero-padded outside domain
    __shared__ float sr4[24][33];
    __shared__ float sr5[12][17];
    __shared__ float sr6[6][9];
    __shared__ float s32p[3][4];    // r7 region * inv
    __shared__ float s64p[3][6];
    __shared__ float s128p[3][10];
    __shared__ float s256p[4][18];
    __shared__ float s512v[6][36];
    __shared__ float s1024[10][68];
    float Ac[3][3], inv;
    load_A(Ag, Ac, inv);
    float wt[4][4];
    make_w44(Ac, wt);

    // issue u row loads first (MLP hides HBM latency under the chain phases)
    int yb = y0 + 8 * w;
    int gyu = yb - 1;
    bool yedge = (gyu < 0) | (gyu + 9 >= n);
    int xm = x0 + 4 * lane;
    int colL = max(xm - 1, 0), colR = min(xm + 4, n - 1);
    bool cornL = (xm - 1 < 0), cornR = (xm + 4 >= n);
    float v[10][6];
#pragma unroll
    for (int rr = 0; rr < 10; ++rr)
        load_row6T<TI>(u, gyu + rr, xm, colL, colR, cornL, cornR, yedge, v[rr]);

    // ---- load r3 region 48x64 at (R3r, R3c) ----
    int R3r = 16 * (by >> 2) - 16, R3c = 32 * bx - 16;
    {
        bool interior = (R3r >= 0) & (R3r + 48 <= 512) & (R3c >= 0) & (R3c + 64 <= 512);
        if (interior) {
            for (int i = t; i < 1536; i += 256) {
                int rr = i >> 5, cc = (i & 31) * 2;
                *(float2*)&sr3[rr][cc] =
                    *(const float2*)&r3[(size_t)(R3r + rr) * 512 + R3c + cc];
            }
        } else {
            for (int i = t; i < 3072; i += 256) {
                int rr = i >> 6, cc = i & 63;
                int gy = R3r + rr, gx = R3c + cc;
                sr3[rr][cc] = (gy >= 0 && gy < 512 && gx >= 0 && gx < 512)
                                  ? r3[(size_t)gy * 512 + gx] : 0.f;
            }
        }
    }
    __syncthreads();
    // ---- region pyramid (identical arithmetic to old multirestrict) ----
    int R4r = 8 * (by >> 2) - 8, R4c = 16 * bx - 8;
    for (int i = t; i < 768; i += 256) {
        int y = i >> 5, x = i & 31;
        sr4[y][x] = 0.25f * (sr3[2 * y][2 * x] + sr3[2 * y][2 * x + 1] +
                             sr3[2 * y + 1][2 * x] + sr3[2 * y + 1][2 * x + 1]);
    }
    __syncthreads();
    int R5r = 4 * (by >> 2) - 4, R5c = 8 * bx - 4;
    if (t < 192) {
        int y = t >> 4, x = t & 15;
        sr5[y][x] = 0.25f * (sr4[2 * y][2 * x] + sr4[2 * y][2 * x + 1] +
                             sr4[2 * y + 1][2 * x] + sr4[2 * y + 1][2 * x + 1]);
    }
    __syncthreads();
    int R6r = 2 * (by >> 2) - 2, R6c = 4 * bx - 2;
    if (t < 48) {
        int y = t >> 3, x = t & 7;
        sr6[y][x] = 0.25f * (sr5[2 * y][2 * x] + sr5[2 * y][2 * x + 1] +
                             sr5[2 * y + 1][2 * x] + sr5[2 * y + 1][2 * x + 1]);
    }
    __syncthreads();
    int R32 = (by >> 2) - 1, C32 = 2 * bx - 1;
    if (t < 12) {
        int y = t >> 2, x = t & 3;
        s32p[y][x] = 0.25f * (sr6[2 * y][2 * x] + sr6[2 * y][2 * x + 1] +
                              sr6[2 * y + 1][2 * x] + sr6[2 * y + 1][2 * x + 1]) * inv;
    }
    __syncthreads();
    // ---- level 64 patch [3][6] ----
    int R64 = (by >> 1) - 1, C64 = 4 * bx - 1;
    if (t < 18) {
        int pr = t / 6, pc = t - (t / 6) * 6;
        int gy = R64 + pr, gx = C64 + pc;
        float val = 0.f;
        if (gy >= 0 && gy < 64 && gx >= 0 && gx < 64) {
            float ctr = s32p[cr(gy) - R32][cr(gx) - C32];
            float sm = 0.f;
#pragma unroll
            for (int dy = -1; dy <= 1; ++dy)
#pragma unroll
                for (int dx = -1; dx <= 1; ++dx) {
                    if (dy == 0 && dx == 0) continue;
                    sm += Ac[dy + 1][dx + 1] * s32p[cr(gy + dy) - R32][cr(gx + dx) - C32];
                }
            val = ctr - sm * inv + sr6[gy - R6r][gx - R6c] * inv;
        }
        s64p[pr][pc] = val;
    }
    __syncthreads();
    // ---- level 128 patch [3][10] ----
    int R128 = by - 1, C128 = 8 * bx - 1;
    if (t < 30) {
        int pr = t / 10, pc = t - (t / 10) * 10;
        int gy = R128 + pr, gx = C128 + pc;
        float val = 0.f;
        if (gy >= 0 && gy < 128 && gx >= 0 && gx < 128) {
            float ctr = s64p[cr(gy) - R64][cr(gx) - C64];
            float sm = 0.f;
#pragma unroll
            for (int dy = -1; dy <= 1; ++dy)
#pragma unroll
                for (int dx = -1; dx <= 1; ++dx) {
                    if (dy == 0 && dx == 0) continue;
                    sm += Ac[dy + 1][dx + 1] * s64p[cr(gy + dy) - R64][cr(gx + dx) - C64];
                }
            val = ctr - sm * inv + sr5[gy - R5r][gx - R5c] * inv;
        }
        s128p[pr][pc] = val;
    }
    __syncthreads();
    // ---- level 256 patch [4][18] ----
    int R256 = 2 * by - 1, C256 = 16 * bx - 1;
    if (t < 72) {
        int pr = t / 18, pc = t - (t / 18) * 18;
        int gy = R256 + pr, gx = C256 + pc;
        float val = 0.f;
        if (gy >= 0 && gy < 256 && gx >= 0 && gx < 256) {
            float ctr = s128p[cr(gy) - R128][cr(gx) - C128];
            float sm = 0.f;
#pragma unroll
            for (int dy = -1; dy <= 1; ++dy)
#pragma unroll
                for (int dx = -1; dx <= 1; ++dx) {
                    if (dy == 0 && dx == 0) continue;
                    sm += Ac[dy + 1][dx + 1] * s128p[cr(gy + dy) - R128][cr(gx + dx) - C128];
                }
            val = ctr - sm * inv + sr4[gy - R4r][gx - R4c] * inv;
        }
        s256p[pr][pc] = val;
    }
    __syncthreads();
    // ---- level 512 patch [6][36] (34 used) ----
    int S5r = 4 * by - 1, S5c = 32 * bx - 1;
    if (t < 216) {
        int pr = t / 36, pc = t - (t / 36) * 36;
        int gy = S5r + pr, gx = S5c + pc;
        float val = 0.f;
        if (pc < 34 && gy >= 0 && gy < 512 && gx >= 0 && gx < 512) {
            float ctr = s256p[cr(gy) - R256][cr(gx) - C256];
            float sm = 0.f;
#pragma unroll
            for (int dy = -1; dy <= 1; ++dy)
#pragma unroll
                for (int dx = -1; dx <= 1; ++dx) {
                    if (dy == 0 && dx == 0) continue;
                    sm += Ac[dy + 1][dx + 1] * s256p[cr(gy + dy) - R256][cr(gx + dx) - C256];
                }
            val = ctr - sm * inv + sr3[gy - R3r][gx - R3c] * inv;
        }
        s512v[pr][pc] = val;
    }
    __syncthreads();
    // ---- level 1024 patch [10][68] (66 used) ----
    int R10 = 8 * by - 1, C10 = 64 * bx - 1;
    for (int i = t; i < 680; i += 256) {
        int pr = i / 68, pc = i - (i / 68) * 68;
        if (pc < 66) {
            int gy = R10 + pr, gx = C10 + pc;
            float val = 0.f;
            if (gy >= 0 && gy < 1024 && gx >= 0 && gx < 1024) {
                float ctr = s512v[cr(gy) - S5r][cr(gx) - S5c];
                float sm = 0.f;
#pragma unroll
                for (int dy = -1; dy <= 1; ++dy)
#pragma unroll
                    for (int dx = -1; dx <= 1; ++dx) {
                        if (dy == 0 && dx == 0) continue;
                        sm += Ac[dy + 1][dx + 1] *
                              s512v[cr(gy + dy) - S5r][cr(gx + dx) - S5c];
                    }
                val = ctr - sm * inv + bf2f(r2[(size_t)gy * 1024 + gx]) * inv;
            }
            s1024[pr][pc] = val;
        }
    }
    __syncthreads();
    // ---- e2048 in regs (r1 recomputed from v[][]) ----
    float e2[4][2];
    int EY0 = 16 * by + 4 * w, EX0 = 128 * bx + 2 * lane;
#pragma unroll
    for (int a = 0; a < 4; ++a) {
        int gy = EY0 + a;
        float a0 = 0.f, a1 = 0.f;
#pragma unroll
        for (int i = 0; i < 4; ++i) {
            const float* vv = v[2 * a + i];
#pragma unroll
            for (int j = 0; j < 4; ++j) {
                a0 += wt[i][j] * vv[j];
                a1 += wt[i][j] * vv[j + 2];
            }
        }
        float r1v[2] = {0.25f * a0, 0.25f * a1};
#pragma unroll
        for (int b = 0; b < 2; ++b) {
            int gx = EX0 + b;
            float ctr = s1024[(gy >> 1) - R10][(gx >> 1) - C10];
            float sm = 0.f;
#pragma unroll
            for (int dy = -1; dy <= 1; ++dy)
#pragma unroll
                for (int dx = -1; dx <= 1; ++dx) {
                    if (dy == 0 && dx == 0) continue;
                    sm += Ac[dy + 1][dx + 1] *
                          s1024[((gy + dy) >> 1) - R10][((gx + dx) >> 1) - C10];
                }
            e2[a][b] = ctr - sm * inv + r1v[b] * inv;
        }
    }
    // ---- u update ----
    float mn = 3.402823466e+38f, mx = -3.402823466e+38f;
#pragma unroll
    for (int r = 0; r < 8; ++r) {
        int y = yb + r;
        const float* va = v[r];
        const float* vb = v[r + 1];
        const float* vc = v[r + 2];
        float out[4];
#pragma unroll
        for (int c = 0; c < 4; ++c) {
            float sm = Ac[0][0] * va[c] + Ac[0][1] * va[c + 1] + Ac[0][2] * va[c + 2]
                     + Ac[1][0] * vb[c]                        + Ac[1][2] * vb[c + 2]
                     + Ac[2][0] * vc[c] + Ac[2][1] * vc[c + 1] + Ac[2][2] * vc[c + 2];
            out[c] = vb[c + 1] - e2[r >> 1][c >> 1] - sm * inv;
        }
        if constexpr (sizeof(TO) == 4) {
            *(float4*)&uo[(size_t)y * n + xm] =
                make_float4(out[0], out[1], out[2], out[3]);
        } else {
            ushort4 o;
            o.x = f2bf(out[0]); o.y = f2bf(out[1]);
            o.z = f2bf(out[2]); o.w = f2bf(out[3]);
            *(ushort4*)&uo[(size_t)y * n + xm] = o;
        }
        if (WANTMM) {
            mn = fminf(mn, fminf(fminf(out[0], out[1]), fminf(out[2], out[3])));
            mx = fmaxf(mx, fmaxf(fmaxf(out[0], out[1]), fmaxf(out[2], out[3])));
        }
    }
    if (WANTMM) {
#pragma unroll
        for (int off = 32; off > 0; off >>= 1) {
            mn = fminf(mn, __shfl_down(mn, off));
            mx = fmaxf(mx, __shfl_down(mx, off));
        }
        __shared__ float smn[4], smx[4];
        if (lane == 0) { smn[w] = mn; smx[w] = mx; }
        __syncthreads();
        if (t == 0) {
            mn = smn[0]; mx = smx[0];
            for (int wq = 1; wq < 4; ++wq) { mn = fminf(mn, smn[wq]); mx = fmaxf(mx, smx[wq]); }
            int bid = by * 16 + bx;
            partials[2 * bid] = mn;
            partials[2 * bid + 1] = mx;
        }
    }
}

// ---- normalize with in-block partials reduction prologue ----
// Grid 2048 x 256; each block reduces all 2048 partial pairs, then streams 8192 elems.
__global__ __launch_bounds__(256) void normalize_kernel(
    const unsigned short* __restrict__ uin, float* __restrict__ uout,
    const float* __restrict__ partials)
{
    int t = threadIdx.x, lane = t & 63, w = t >> 6;
    float mn = 3.402823466e+38f, mx = -3.402823466e+38f;
    for (int i = t; i < 2048; i += 256) {
        mn = fminf(mn, partials[2 * i]);
        mx = fmaxf(mx, partials[2 * i + 1]);
    }
#pragma unroll
    for (int off = 32; off > 0; off >>= 1) {
        mn = fminf(mn, __shfl_down(mn, off));
        mx = fmaxf(mx, __shfl_down(mx, off));
    }
    __shared__ float smn[4], smx[4];
    __shared__ float mmv[2];
    if (lane == 0) { smn[w] = mn; smx[w] = mx; }
    __syncthreads();
    if (t == 0) {
        mn = smn[0]; mx = smx[0];
        for (int wq = 1; wq < 4; ++wq) { mn = fminf(mn, smn[wq]); mx = fmaxf(mx, smx[wq]); }
        mmv[0] = mn;
        mmv[1] = 1.0f / (mx - mn);
    }
    __syncthreads();
    float mnv = mmv[0], sc = mmv[1];
    size_t base = (size_t)blockIdx.x * 8192;
#pragma unroll
    for (int k = 0; k < 8; ++k) {
        size_t i = base + (size_t)k * 1024 + t * 4;
        ushort4 h = *(const ushort4*)&uin[i];
        float4 o;
        o.x = (bf2f(h.x) - mnv) * sc;
        o.y = (bf2f(h.y) - mnv) * sc;
        o.z = (bf2f(h.z) - mnv) * sc;
        o.w = (bf2f(h.w) - mnv) * sc;
        *(float4*)&uout[i] = o;
    }
}

extern "C" void kernel_launch(void* const* d_in, const int* in_sizes, int n_in,
                              void* d_out, int out_size, void* d_ws, size_t ws_size,
                              hipStream_t stream)
{
    const float* A  = (const float*)d_in[0];
    const float* u0 = (const float*)d_in[1];
    float* uout = (float*)d_out;
    char* ws = (char*)d_ws;

    size_t off = 0;
    auto alloc_f = [&](size_t nelem) { float* p = (float*)(ws + off); off += nelem * 4; return p; };
    float* r3 = alloc_f(512ull * 512);
    float* partials = alloc_f(4096);
    off = (off + 15) & ~15ull;
    unsigned short* r2 = (unsigned short*)(ws + off); off += 1024ull * 1024 * 2;
    off = (off + 15) & ~15ull;
    unsigned short* ubA = (unsigned short*)(ws + off); off += 4096ull * 4096 * 2;
    unsigned short* ubB = (unsigned short*)(ws + off); off += 4096ull * 4096 * 2;

    // it0: u0(f32) -> ubA ; it1: ubA -> ubB ; it2: ubB -> ubA ; it3: ubA -> ubB(bf16)
    for (int it = 0; it < 4; ++it) {
        if (it == 0) {
            smooth_restrict2_kernel<float><<<2048, 256, 0, stream>>>(u0, A, r2, r3);
        } else {
            const unsigned short* us = (it == 2) ? ubB : ubA;
            smooth_restrict2_kernel<unsigned short><<<2048, 256, 0, stream>>>(us, A, r2, r3);
        }
        if (it == 0) {
            final_fused_kernel<float, unsigned short, false><<<2048, 256, 0, stream>>>(
                u0, r3, r2, A, ubA, partials);
        } else if (it == 1) {
            final_fused_kernel<unsigned short, unsigned short, false><<<2048, 256, 0, stream>>>(
                ubA, r3, r2, A, ubB, partials);
        } else if (it == 2) {
            final_fused_kernel<unsigned short, unsigned short, false><<<2048, 256, 0, stream>>>(
                ubB, r3, r2, A, ubA, partials);
        } else {
            final_fused_kernel<unsigned short, unsigned short, true><<<2048, 256, 0, stream>>>(
                ubA, r3, r2, A, ubB, partials);
        }
    }
    normalize_kernel<<<2048, 256, 0, stream>>>(ubB, uout, partials);
}

// Round 16
// 175.086 us; speedup vs baseline: 1.0423x; 1.0423x over previous
//
#include <hip/hip_runtime.h>

#define N 4096

__device__ __forceinline__ float bf2f(unsigned short h)
{
    unsigned int u = ((unsigned int)h) << 16;
    return __uint_as_float(u);
}
__device__ __forceinline__ unsigned short f2bf(float f)
{
    unsigned int x = __float_as_uint(f);
    unsigned int r = (x + 0x7FFFu + ((x >> 16) & 1u)) >> 16;  // round-nearest-even
    return (unsigned short)r;
}

// floor(i/2) valid for i >= -1024
__device__ __forceinline__ int cr(int i) { return ((i + 1024) >> 1) - 512; }

__device__ __forceinline__ void load_A(const float* __restrict__ Ag,
                                       float Ac[3][3], float& inv)
{
#pragma unroll
    for (int i = 0; i < 9; ++i) Ac[i / 3][i % 3] = Ag[i];
    inv = 1.0f / Ac[1][1];
    Ac[1][1] = 0.f;
}

__device__ __forceinline__ void make_w44(const float Ac[3][3], float wt[4][4])
{
#pragma unroll
    for (int a = 0; a < 4; ++a)
#pragma unroll
        for (int b = 0; b < 4; ++b) wt[a][b] = 0.f;
#pragma unroll
    for (int r = 0; r < 2; ++r)
#pragma unroll
        for (int c = 0; c < 2; ++c)
#pragma unroll
            for (int i = 0; i < 3; ++i)
#pragma unroll
                for (int j = 0; j < 3; ++j) wt[r + i][c + j] += Ac[i][j];
}

// Branch-free u_bc row segment (f32 or bf16 storage; math in f32).
template <typename TI>
__device__ __forceinline__ void load_row6T(const TI* __restrict__ u,
                                           int gy, int xm, int colL, int colR,
                                           bool cornL, bool cornR, bool yedge,
                                           float v[6])
{
    int cy = min(max(gy, 0), N - 1);
    const TI* rowp = &u[(size_t)cy * N];
    float L, R;
    if constexpr (sizeof(TI) == 4) {
        float4 m = *(const float4*)&rowp[xm];
        v[1] = m.x; v[2] = m.y; v[3] = m.z; v[4] = m.w;
        L = rowp[colL];
        R = rowp[colR];
    } else {
        ushort4 m = *(const ushort4*)&rowp[xm];
        v[1] = bf2f(m.x); v[2] = bf2f(m.y); v[3] = bf2f(m.z); v[4] = bf2f(m.w);
        L = bf2f(rowp[colL]);
        R = bf2f(rowp[colR]);
    }
    if (yedge) {
        bool oob = (gy < 0) | (gy >= N);
        if (oob & cornL) L = 0.f;
        if (oob & cornR) R = 0.f;
    }
    v[0] = L; v[5] = R;
}

// XCD-aware bijective swizzle for 2048-block 1D grids (2048 % 8 == 0).
__device__ __forceinline__ void swz2048(int bid, int& bx, int& by)
{
    int reg = (bid & 7) * 256 + (bid >> 3);
    bx = reg & 15;
    by = reg >> 4;
}

// ---- fused smooth(bc(u)) + restrict + restrict -> r2(bf16, 1024^2) + r3(f32, 512^2) ----
template <typename TI>
__global__ __launch_bounds__(256) void smooth_restrict2_kernel(
    const TI* __restrict__ u, const float* __restrict__ Ag,
    unsigned short* __restrict__ r2, float* __restrict__ r3)
{
    int t = threadIdx.x, lane = t & 63, w = t >> 6;
    int bx, by;
    swz2048(blockIdx.x, bx, by);
    int x0 = 256 * bx;
    int Y0 = 16 * by + 4 * w;
    int gy0 = 2 * Y0 - 1;
    bool yedge = (gy0 < 0) | (gy0 + 9 >= N);
    float Ac[3][3], inv;
    load_A(Ag, Ac, inv);
    float wt[4][4];
    make_w44(Ac, wt);

    int xm = x0 + 4 * lane;
    int colL = max(xm - 1, 0), colR = min(xm + 4, N - 1);
    bool cornL = (xm - 1 < 0), cornR = (xm + 4 >= N);
    float v[10][6];
#pragma unroll
    for (int rr = 0; rr < 10; ++rr)
        load_row6T<TI>(u, gy0 + rr, xm, colL, colR, cornL, cornR, yedge, v[rr]);

    float o0[4], o1[4];
#pragma unroll
    for (int q = 0; q < 4; ++q) {
        float a0 = 0.f, a1 = 0.f;
#pragma unroll
        for (int a = 0; a < 4; ++a) {
            const float* vv = v[2 * q + a];
#pragma unroll
            for (int b = 0; b < 4; ++b) {
                a0 += wt[a][b] * vv[b];
                a1 += wt[a][b] * vv[b + 2];
            }
        }
        o0[q] = 0.25f * a0;
        o1[q] = 0.25f * a1;
    }
    int Y2 = Y0 >> 1, X2 = 64 * bx + lane;   // Y2 even
    float val0 = 0.25f * (o0[0] + o1[0] + o0[1] + o1[1]);
    float val1 = 0.25f * (o0[2] + o1[2] + o0[3] + o1[3]);
    r2[(size_t)Y2 * 1024 + X2] = f2bf(val0);
    r2[(size_t)(Y2 + 1) * 1024 + X2] = f2bf(val1);
    float s0 = val0 + val1;
    float s1 = __shfl_xor(s0, 1);
    if (!(lane & 1))
        r3[(size_t)(Y2 >> 1) * 512 + (X2 >> 1)] = 0.25f * (s0 + s1);
}

// ---- restriction tree: r3 -> r4..r7 (grid 16x16) ----
__global__ __launch_bounds__(256) void multirestrict_kernel(
    const float* __restrict__ r3, float* __restrict__ r4, float* __restrict__ r5,
    float* __restrict__ r6, float* __restrict__ r7)
{
    int BX = blockIdx.x, BY = blockIdx.y;
    __shared__ float s4[16][17];
    __shared__ float s5[8][9];
    __shared__ float s6[4][5];
    int t = threadIdx.x;
    {
        int y = t >> 4, x = t & 15;
        const float* b0 = &r3[(size_t)(32 * BY + 2 * y) * 512 + 32 * BX + 2 * x];
        float2 a = *(const float2*)b0;
        float2 b = *(const float2*)(b0 + 512);
        float vv = 0.25f * (a.x + a.y + b.x + b.y);
        r4[(size_t)(16 * BY + y) * 256 + 16 * BX + x] = vv;
        s4[y][x] = vv;
    }
    __syncthreads();
    if (t < 64) {
        int y = t >> 3, x = t & 7;
        float vv = 0.25f * (s4[2 * y][2 * x] + s4[2 * y][2 * x + 1] +
                            s4[2 * y + 1][2 * x] + s4[2 * y + 1][2 * x + 1]);
        r5[(size_t)(8 * BY + y) * 128 + 8 * BX + x] = vv;
        s5[y][x] = vv;
    }
    __syncthreads();
    if (t < 16) {
        int y = t >> 2, x = t & 3;
        float vv = 0.25f * (s5[2 * y][2 * x] + s5[2 * y][2 * x + 1] +
                            s5[2 * y + 1][2 * x] + s5[2 * y + 1][2 * x + 1]);
        r6[(size_t)(4 * BY + y) * 64 + 4 * BX + x] = vv;
        s6[y][x] = vv;
    }
    __syncthreads();
    if (t < 4) {
        int y = t >> 1, x = t & 1;
        float vv = 0.25f * (s6[2 * y][2 * x] + s6[2 * y][2 * x + 1] +
                            s6[2 * y + 1][2 * x] + s6[2 * y + 1][2 * x + 1]);
        r7[(size_t)(2 * BY + y) * 32 + 2 * BX + x] = vv;
    }
}

// ---- fused: full coarse e-chain (r7..r3 patches) -> e1024 -> e2048(regs) -> u update ----
// TI/TO: float or ushort(bf16) storage for u_in / u_out. r2 stored bf16.
template <typename TI, typename TO, bool WANTMM>
__global__ __launch_bounds__(256) void final_fused_kernel(
    const TI* __restrict__ u,
    const float* __restrict__ r7, const float* __restrict__ r6,
    const float* __restrict__ r5, const float* __restrict__ r4,
    const float* __restrict__ r3, const unsigned short* __restrict__ r2,
    const float* __restrict__ Ag, TO* __restrict__ uo,
    float* __restrict__ partials)
{
    const int n = N;
    int t = threadIdx.x, lane = t & 63, w = t >> 6;
    int bx, by;
    swz2048(blockIdx.x, bx, by);
    int x0 = 256 * bx, y0 = 32 * by;
    __shared__ float s32p[3][4];     // e32 = r7/diag, zero-padded halo
    __shared__ float s64p[3][6];
    __shared__ float s128p[3][10];
    __shared__ float s256p[4][18];
    __shared__ float s512v[6][36];
    __shared__ float s1024[10][68];
    float Ac[3][3], inv;
    load_A(Ag, Ac, inv);
    float wt[4][4];
    make_w44(Ac, wt);

    // issue u row loads first (MLP hides HBM latency under the e-chain phases)
    int yb = y0 + 8 * w;
    int gyu = yb - 1;
    bool yedge = (gyu < 0) | (gyu + 9 >= n);
    int xm = x0 + 4 * lane;
    int colL = max(xm - 1, 0), colR = min(xm + 4, n - 1);
    bool cornL = (xm - 1 < 0), cornR = (xm + 4 >= n);
    float v[10][6];
#pragma unroll
    for (int rr = 0; rr < 10; ++rr)
        load_row6T<TI>(u, gyu + rr, xm, colL, colR, cornL, cornR, yedge, v[rr]);

    // ---- level 32: r7/diag patch [3][4] ----
    int R32 = (by >> 2) - 1, C32 = 2 * bx - 1;
    if (t < 12) {
        int pr = t >> 2, pc = t & 3;
        int gy = R32 + pr, gx = C32 + pc;
        s32p[pr][pc] = (gy >= 0 && gy < 32 && gx >= 0 && gx < 32)
                           ? r7[(size_t)gy * 32 + gx] * inv : 0.f;
    }
    __syncthreads();
    // ---- level 64 patch [3][6] ----
    int R64 = (by >> 1) - 1, C64 = 4 * bx - 1;
    if (t < 18) {
        int pr = t / 6, pc = t - (t / 6) * 6;
        int gy = R64 + pr, gx = C64 + pc;
        float val = 0.f;
        if (gy >= 0 && gy < 64 && gx >= 0 && gx < 64) {
            float ctr = s32p[cr(gy) - R32][cr(gx) - C32];
            float sm = 0.f;
#pragma unroll
            for (int dy = -1; dy <= 1; ++dy)
#pragma unroll
                for (int dx = -1; dx <= 1; ++dx) {
                    if (dy == 0 && dx == 0) continue;
                    sm += Ac[dy + 1][dx + 1] * s32p[cr(gy + dy) - R32][cr(gx + dx) - C32];
                }
            val = ctr - sm * inv + r6[(size_t)gy * 64 + gx] * inv;
        }
        s64p[pr][pc] = val;
    }
    __syncthreads();
    // ---- level 128 patch [3][10] ----
    int R128 = by - 1, C128 = 8 * bx - 1;
    if (t < 30) {
        int pr = t / 10, pc = t - (t / 10) * 10;
        int gy = R128 + pr, gx = C128 + pc;
        float val = 0.f;
        if (gy >= 0 && gy < 128 && gx >= 0 && gx < 128) {
            float ctr = s64p[cr(gy) - R64][cr(gx) - C64];
            float sm = 0.f;
#pragma unroll
            for (int dy = -1; dy <= 1; ++dy)
#pragma unroll
                for (int dx = -1; dx <= 1; ++dx) {
                    if (dy == 0 && dx == 0) continue;
                    sm += Ac[dy + 1][dx + 1] * s64p[cr(gy + dy) - R64][cr(gx + dx) - C64];
                }
            val = ctr - sm * inv + r5[(size_t)gy * 128 + gx] * inv;
        }
        s128p[pr][pc] = val;
    }
    __syncthreads();
    // ---- level 256 patch [4][18] ----
    int R256 = 2 * by - 1, C256 = 16 * bx - 1;
    if (t < 72) {
        int pr = t / 18, pc = t - (t / 18) * 18;
        int gy = R256 + pr, gx = C256 + pc;
        float val = 0.f;
        if (gy >= 0 && gy < 256 && gx >= 0 && gx < 256) {
            float ctr = s128p[cr(gy) - R128][cr(gx) - C128];
            float sm = 0.f;
#pragma unroll
            for (int dy = -1; dy <= 1; ++dy)
#pragma unroll
                for (int dx = -1; dx <= 1; ++dx) {
                    if (dy == 0 && dx == 0) continue;
                    sm += Ac[dy + 1][dx + 1] * s128p[cr(gy + dy) - R128][cr(gx + dx) - C128];
                }
            val = ctr - sm * inv + r4[(size_t)gy * 256 + gx] * inv;
        }
        s256p[pr][pc] = val;
    }
    __syncthreads();
    // ---- level 512 patch [6][36] (34 used) ----
    int S5r = 4 * by - 1, S5c = 32 * bx - 1;
    if (t < 216) {
        int pr = t / 36, pc = t - (t / 36) * 36;
        int gy = S5r + pr, gx = S5c + pc;
        float val = 0.f;
        if (pc < 34 && gy >= 0 && gy < 512 && gx >= 0 && gx < 512) {
            float ctr = s256p[cr(gy) - R256][cr(gx) - C256];
            float sm = 0.f;
#pragma unroll
            for (int dy = -1; dy <= 1; ++dy)
#pragma unroll
                for (int dx = -1; dx <= 1; ++dx) {
                    if (dy == 0 && dx == 0) continue;
                    sm += Ac[dy + 1][dx + 1] * s256p[cr(gy + dy) - R256][cr(gx + dx) - C256];
                }
            val = ctr - sm * inv + r3[(size_t)gy * 512 + gx] * inv;
        }
        s512v[pr][pc] = val;
    }
    __syncthreads();
    // ---- level 1024 patch [10][68] (66 used) ----
    int R10 = 8 * by - 1, C10 = 64 * bx - 1;
    for (int i = t; i < 680; i += 256) {
        int pr = i / 68, pc = i - (i / 68) * 68;
        if (pc < 66) {
            int gy = R10 + pr, gx = C10 + pc;
            float val = 0.f;
            if (gy >= 0 && gy < 1024 && gx >= 0 && gx < 1024) {
                float ctr = s512v[cr(gy) - S5r][cr(gx) - S5c];
                float sm = 0.f;
#pragma unroll
                for (int dy = -1; dy <= 1; ++dy)
#pragma unroll
                    for (int dx = -1; dx <= 1; ++dx) {
                        if (dy == 0 && dx == 0) continue;
                        sm += Ac[dy + 1][dx + 1] *
                              s512v[cr(gy + dy) - S5r][cr(gx + dx) - S5c];
                    }
                val = ctr - sm * inv + bf2f(r2[(size_t)gy * 1024 + gx]) * inv;
            }
            s1024[pr][pc] = val;
        }
    }
    __syncthreads();
    // ---- e2048 in regs (r1 recomputed from v[][]) ----
    float e2[4][2];
    int EY0 = 16 * by + 4 * w, EX0 = 128 * bx + 2 * lane;
#pragma unroll
    for (int a = 0; a < 4; ++a) {
        int gy = EY0 + a;
        float a0 = 0.f, a1 = 0.f;
#pragma unroll
        for (int i = 0; i < 4; ++i) {
            const float* vv = v[2 * a + i];
#pragma unroll
            for (int j = 0; j < 4; ++j) {
                a0 += wt[i][j] * vv[j];
                a1 += wt[i][j] * vv[j + 2];
            }
        }
        float r1v[2] = {0.25f * a0, 0.25f * a1};
#pragma unroll
        for (int b = 0; b < 2; ++b) {
            int gx = EX0 + b;
            float ctr = s1024[(gy >> 1) - R10][(gx >> 1) - C10];
            float sm = 0.f;
#pragma unroll
            for (int dy = -1; dy <= 1; ++dy)
#pragma unroll
                for (int dx = -1; dx <= 1; ++dx) {
                    if (dy == 0 && dx == 0) continue;
                    sm += Ac[dy + 1][dx + 1] *
                          s1024[((gy + dy) >> 1) - R10][((gx + dx) >> 1) - C10];
                }
            e2[a][b] = ctr - sm * inv + r1v[b] * inv;
        }
    }
    // ---- u update ----
    float mn = 3.402823466e+38f, mx = -3.402823466e+38f;
#pragma unroll
    for (int r = 0; r < 8; ++r) {
        int y = yb + r;
        const float* va = v[r];
        const float* vb = v[r + 1];
        const float* vc = v[r + 2];
        float out[4];
#pragma unroll
        for (int c = 0; c < 4; ++c) {
            float sm = Ac[0][0] * va[c] + Ac[0][1] * va[c + 1] + Ac[0][2] * va[c + 2]
                     + Ac[1][0] * vb[c]                        + Ac[1][2] * vb[c + 2]
                     + Ac[2][0] * vc[c] + Ac[2][1] * vc[c + 1] + Ac[2][2] * vc[c + 2];
            out[c] = vb[c + 1] - e2[r >> 1][c >> 1] - sm * inv;
        }
        if constexpr (sizeof(TO) == 4) {
            *(float4*)&uo[(size_t)y * n + xm] =
                make_float4(out[0], out[1], out[2], out[3]);
        } else {
            ushort4 o;
            o.x = f2bf(out[0]); o.y = f2bf(out[1]);
            o.z = f2bf(out[2]); o.w = f2bf(out[3]);
            *(ushort4*)&uo[(size_t)y * n + xm] = o;
        }
        if (WANTMM) {
            mn = fminf(mn, fminf(fminf(out[0], out[1]), fminf(out[2], out[3])));
            mx = fmaxf(mx, fmaxf(fmaxf(out[0], out[1]), fmaxf(out[2], out[3])));
        }
    }
    if (WANTMM) {
#pragma unroll
        for (int off = 32; off > 0; off >>= 1) {
            mn = fminf(mn, __shfl_down(mn, off));
            mx = fmaxf(mx, __shfl_down(mx, off));
        }
        __shared__ float smn[4], smx[4];
        if (lane == 0) { smn[w] = mn; smx[w] = mx; }
        __syncthreads();
        if (t == 0) {
            mn = smn[0]; mx = smx[0];
            for (int wq = 1; wq < 4; ++wq) { mn = fminf(mn, smn[wq]); mx = fmaxf(mx, smx[wq]); }
            int bid = by * 16 + bx;
            partials[2 * bid] = mn;
            partials[2 * bid + 1] = mx;
        }
    }
}

// ---- normalize with in-block partials reduction prologue ----
// Grid 2048 x 256; each block reduces all 2048 partial pairs, then streams 8192 elems.
__global__ __launch_bounds__(256) void normalize_kernel(
    const unsigned short* __restrict__ uin, float* __restrict__ uout,
    const float* __restrict__ partials)
{
    int t = threadIdx.x, lane = t & 63, w = t >> 6;
    float mn = 3.402823466e+38f, mx = -3.402823466e+38f;
    for (int i = t; i < 2048; i += 256) {
        mn = fminf(mn, partials[2 * i]);
        mx = fmaxf(mx, partials[2 * i + 1]);
    }
#pragma unroll
    for (int off = 32; off > 0; off >>= 1) {
        mn = fminf(mn, __shfl_down(mn, off));
        mx = fmaxf(mx, __shfl_down(mx, off));
    }
    __shared__ float smn[4], smx[4];
    __shared__ float mmv[2];
    if (lane == 0) { smn[w] = mn; smx[w] = mx; }
    __syncthreads();
    if (t == 0) {
        mn = smn[0]; mx = smx[0];
        for (int wq = 1; wq < 4; ++wq) { mn = fminf(mn, smn[wq]); mx = fmaxf(mx, smx[wq]); }
        mmv[0] = mn;
        mmv[1] = 1.0f / (mx - mn);
    }
    __syncthreads();
    float mnv = mmv[0], sc = mmv[1];
    size_t base = (size_t)blockIdx.x * 8192;
#pragma unroll
    for (int k = 0; k < 8; ++k) {
        size_t i = base + (size_t)k * 1024 + t * 4;
        ushort4 h = *(const ushort4*)&uin[i];
        float4 o;
        o.x = (bf2f(h.x) - mnv) * sc;
        o.y = (bf2f(h.y) - mnv) * sc;
        o.z = (bf2f(h.z) - mnv) * sc;
        o.w = (bf2f(h.w) - mnv) * sc;
        *(float4*)&uout[i] = o;
    }
}

extern "C" void kernel_launch(void* const* d_in, const int* in_sizes, int n_in,
                              void* d_out, int out_size, void* d_ws, size_t ws_size,
                              hipStream_t stream)
{
    const float* A  = (const float*)d_in[0];
    const float* u0 = (const float*)d_in[1];
    float* uout = (float*)d_out;
    char* ws = (char*)d_ws;

    size_t off = 0;
    auto alloc_f = [&](size_t nelem) { float* p = (float*)(ws + off); off += nelem * 4; return p; };
    float* r3 = alloc_f(512ull * 512);
    float* r4 = alloc_f(256ull * 256);
    float* r5 = alloc_f(128ull * 128);
    float* r6 = alloc_f(64ull * 64);
    float* r7 = alloc_f(32ull * 32);
    float* partials = alloc_f(4096);
    off = (off + 15) & ~15ull;
    unsigned short* r2 = (unsigned short*)(ws + off); off += 1024ull * 1024 * 2;
    off = (off + 15) & ~15ull;
    unsigned short* ubA = (unsigned short*)(ws + off); off += 4096ull * 4096 * 2;
    unsigned short* ubB = (unsigned short*)(ws + off); off += 4096ull * 4096 * 2;

    // it0: u0(f32) -> ubA ; it1: ubA -> ubB ; it2: ubB -> ubA ; it3: ubA -> ubB(bf16)
    for (int it = 0; it < 4; ++it) {
        if (it == 0) {
            smooth_restrict2_kernel<float><<<2048, 256, 0, stream>>>(u0, A, r2, r3);
        } else {
            const unsigned short* us = (it == 2) ? ubB : ubA;
            smooth_restrict2_kernel<unsigned short><<<2048, 256, 0, stream>>>(us, A, r2, r3);
        }
        multirestrict_kernel<<<dim3(16, 16), 256, 0, stream>>>(r3, r4, r5, r6, r7);
        if (it == 0) {
            final_fused_kernel<float, unsigned short, false><<<2048, 256, 0, stream>>>(
                u0, r7, r6, r5, r4, r3, r2, A, ubA, partials);
        } else if (it == 1) {
            final_fused_kernel<unsigned short, unsigned short, false><<<2048, 256, 0, stream>>>(
                ubA, r7, r6, r5, r4, r3, r2, A, ubB, partials);
        } else if (it == 2) {
            final_fused_kernel<unsigned short, unsigned short, false><<<2048, 256, 0, stream>>>(
                ubB, r7, r6, r5, r4, r3, r2, A, ubA, partials);
        } else {
            final_fused_kernel<unsigned short, unsigned short, true><<<2048, 256, 0, stream>>>(
                ubA, r7, r6, r5, r4, r3, r2, A, ubB, partials);
        }
    }
    normalize_kernel<<<2048, 256, 0, stream>>>(ubB, uout, partials);
}